// Round 1
// baseline (189.983 us; speedup 1.0000x reference)
//
#include <hip/hip_runtime.h>
#include <hip/hip_bf16.h>

#define NROW 8192
#define DDIM 1024
#define TINV 2.0f   // 1 / TEMPERATURE

typedef __attribute__((ext_vector_type(4))) float f32x4;
typedef __attribute__((ext_vector_type(8))) short short8;

__device__ __forceinline__ ushort f2bf(float f) {
  union { float f; unsigned u; } x; x.f = f;
  unsigned r = x.u + 0x7fffu + ((x.u >> 16) & 1u);  // RNE
  return (ushort)(r >> 16);
}

__device__ __forceinline__ void gload_lds16(const void* g, void* l) {
  __builtin_amdgcn_global_load_lds(
      (const __attribute__((address_space(1))) void*)g,
      (__attribute__((address_space(3))) void*)l, 16, 0, 0);
}

// ---------------------------------------------------------------------------
// Kernel 1: per-row L2 norms, diag, bf16 normalized copies.
// z1 is pre-scaled by 1/T so the GEMM directly produces sim.
// ---------------------------------------------------------------------------
__global__ __launch_bounds__(256) void normalize_diag(
    const float* __restrict__ v1, const float* __restrict__ v2,
    ushort* __restrict__ z1, ushort* __restrict__ z2,
    float* __restrict__ diag)
{
  const int row = blockIdx.x;
  const int t = threadIdx.x;
  const float4 a = ((const float4*)(v1 + (size_t)row * DDIM))[t];
  const float4 b = ((const float4*)(v2 + (size_t)row * DDIM))[t];
  float s1 = a.x*a.x + a.y*a.y + a.z*a.z + a.w*a.w;
  float s2 = b.x*b.x + b.y*b.y + b.z*b.z + b.w*b.w;
  float sd = a.x*b.x + a.y*b.y + a.z*b.z + a.w*b.w;
  #pragma unroll
  for (int m = 1; m < 64; m <<= 1) {
    s1 += __shfl_xor(s1, m);
    s2 += __shfl_xor(s2, m);
    sd += __shfl_xor(sd, m);
  }
  __shared__ float red[3][4];
  const int w = t >> 6;
  if ((t & 63) == 0) { red[0][w] = s1; red[1][w] = s2; red[2][w] = sd; }
  __syncthreads();
  s1 = red[0][0] + red[0][1] + red[0][2] + red[0][3];
  s2 = red[1][0] + red[1][1] + red[1][2] + red[1][3];
  sd = red[2][0] + red[2][1] + red[2][2] + red[2][3];
  const float n1 = fmaxf(sqrtf(s1), 1e-12f);
  const float n2 = fmaxf(sqrtf(s2), 1e-12f);
  const float i1 = 1.0f / n1, i2 = 1.0f / n2;
  if (t == 0) diag[row] = sd * i1 * i2 * TINV;
  const float sc1 = i1 * TINV;  // fold 1/T into z1
  ushort4 o1, o2;
  o1.x = f2bf(a.x * sc1); o1.y = f2bf(a.y * sc1);
  o1.z = f2bf(a.z * sc1); o1.w = f2bf(a.w * sc1);
  o2.x = f2bf(b.x * i2);  o2.y = f2bf(b.y * i2);
  o2.z = f2bf(b.z * i2);  o2.w = f2bf(b.w * i2);
  ((ushort4*)(z1 + (size_t)row * DDIM))[t] = o1;
  ((ushort4*)(z2 + (size_t)row * DDIM))[t] = o2;
}

// ---------------------------------------------------------------------------
// Kernel 2: sim = z1 * z2^T (both row-major over K), fused exp-rowsum.
// m97 structure: 128x128 tile, BK=32, 4 waves, global_load_lds width 16.
// Each block writes partial[bj][brow..brow+127] (exactly once, no atomics).
// ---------------------------------------------------------------------------
#define BM 128
#define BN 128
#define BK 32

__global__ __launch_bounds__(256) void gemm_rowsum(
    const ushort* __restrict__ z1, const ushort* __restrict__ z2,
    float* __restrict__ partial)
{
  __shared__ ushort As[BM * BK];
  __shared__ ushort Bs[BN * BK];
  __shared__ float rs_lds[2][BM];

  const int bid = blockIdx.x;
  const int bi = bid >> 6;        // 64 row-blocks
  const int bj = bid & 63;        // 64 col-blocks
  const int brow = bi * BM;
  const int bcol = bj * BN;
  const int t = threadIdx.x;
  const int wave = t >> 6;
  const int lane = t & 63;
  const int wr = wave >> 1;       // wave row 0..1 (64 rows each)
  const int wc = wave & 1;        // wave col 0..1 (64 cols each)
  const int lcol = lane & 15;
  const int lgrp = lane >> 4;

  f32x4 acc[4][4];
  #pragma unroll
  for (int i = 0; i < 4; ++i)
    #pragma unroll
    for (int j = 0; j < 4; ++j)
      acc[i][j] = (f32x4){0.f, 0.f, 0.f, 0.f};

  // staging geometry: per issue a wave loads 16 rows x 32 cols (64 lanes x 8 bf16)
  const int srow = lane >> 2;         // 0..15
  const int scol = (lane & 3) * 8;    // 0,8,16,24

  for (int k0 = 0; k0 < DDIM; k0 += BK) {
    __syncthreads();   // all waves done reading LDS from previous step
    #pragma unroll
    for (int i = 0; i < 2; ++i) {
      const int r0 = i * 64 + wave * 16;
      gload_lds16(z1 + ((size_t)(brow + r0 + srow)) * DDIM + k0 + scol,
                  &As[r0 * BK]);
      gload_lds16(z2 + ((size_t)(bcol + r0 + srow)) * DDIM + k0 + scol,
                  &Bs[r0 * BK]);
    }
    __syncthreads();   // compiler drains vmcnt before barrier -> tiles ready

    short8 af[4], bfr[4];
    #pragma unroll
    for (int mi = 0; mi < 4; ++mi)
      af[mi] = *(const short8*)&As[(wr * 64 + mi * 16 + lcol) * BK + lgrp * 8];
    #pragma unroll
    for (int ni = 0; ni < 4; ++ni)
      bfr[ni] = *(const short8*)&Bs[(wc * 64 + ni * 16 + lcol) * BK + lgrp * 8];
    #pragma unroll
    for (int mi = 0; mi < 4; ++mi)
      #pragma unroll
      for (int ni = 0; ni < 4; ++ni)
        acc[mi][ni] = __builtin_amdgcn_mfma_f32_16x16x32_bf16(
            af[mi], bfr[ni], acc[mi][ni], 0, 0, 0);
  }

  // Epilogue: exp + per-row sum over this block's 128 cols.
  // C/D layout (measured): col = lane&15, row = (lane>>4)*4 + reg.
  #pragma unroll
  for (int mi = 0; mi < 4; ++mi) {
    #pragma unroll
    for (int r = 0; r < 4; ++r) {
      float s = __expf(acc[mi][0][r]) + __expf(acc[mi][1][r])
              + __expf(acc[mi][2][r]) + __expf(acc[mi][3][r]);
      s += __shfl_xor(s, 1);
      s += __shfl_xor(s, 2);
      s += __shfl_xor(s, 4);
      s += __shfl_xor(s, 8);
      if (lcol == 0)
        rs_lds[wc][wr * 64 + mi * 16 + lgrp * 4 + r] = s;
    }
  }
  __syncthreads();
  if (t < BM)
    partial[(size_t)bj * NROW + brow + t] = rs_lds[0][t] + rs_lds[1][t];
}

// ---------------------------------------------------------------------------
// Kernel 3: per-row loss = log(sum of 64 partials) - diag; block partial sums.
// ---------------------------------------------------------------------------
__global__ __launch_bounds__(256) void rowloss(
    const float* __restrict__ partial, const float* __restrict__ diag,
    float* __restrict__ blocksum)
{
  const int i = blockIdx.x * 256 + threadIdx.x;
  float s = 0.f;
  #pragma unroll 8
  for (int b = 0; b < 64; ++b) s += partial[(size_t)b * NROW + i];
  float loss = logf(s) - diag[i];
  #pragma unroll
  for (int m = 1; m < 64; m <<= 1) loss += __shfl_xor(loss, m);
  __shared__ float red[4];
  if ((threadIdx.x & 63) == 0) red[threadIdx.x >> 6] = loss;
  __syncthreads();
  if (threadIdx.x == 0)
    blocksum[blockIdx.x] = red[0] + red[1] + red[2] + red[3];
}

__global__ void finalize(const float* __restrict__ blocksum,
                         float* __restrict__ out)
{
  float s = (threadIdx.x < 32) ? blocksum[threadIdx.x] : 0.f;
  #pragma unroll
  for (int m = 1; m < 64; m <<= 1) s += __shfl_xor(s, m);
  if (threadIdx.x == 0) out[0] = s * (1.0f / NROW);
}

// ---------------------------------------------------------------------------
extern "C" void kernel_launch(void* const* d_in, const int* in_sizes, int n_in,
                              void* d_out, int out_size, void* d_ws, size_t ws_size,
                              hipStream_t stream) {
  const float* v1 = (const float*)d_in[0];
  const float* v2 = (const float*)d_in[1];
  float* out = (float*)d_out;

  char* ws = (char*)d_ws;
  // layout: z1 (16MB) | z2 (16MB) | diag (32KB) | partial (2MB) | blocksum (128B)
  ushort* z1 = (ushort*)ws;
  ushort* z2 = (ushort*)(ws + (size_t)NROW * DDIM * 2);
  float* diag = (float*)(ws + (size_t)NROW * DDIM * 4);
  float* partial = (float*)(ws + (size_t)NROW * DDIM * 4 + (size_t)NROW * 4);
  float* blocksum = (float*)(ws + (size_t)NROW * DDIM * 4 + (size_t)NROW * 4
                             + (size_t)64 * NROW * 4);

  normalize_diag<<<NROW, 256, 0, stream>>>(v1, v2, z1, z2, diag);
  gemm_rowsum<<<(NROW / BM) * (NROW / BN), 256, 0, stream>>>(z1, z2, partial);
  rowloss<<<NROW / 256, 256, 0, stream>>>(partial, diag, blocksum);
  finalize<<<1, 64, 0, stream>>>(blocksum, out);
}

// Round 2
// 170.174 us; speedup vs baseline: 1.1164x; 1.1164x over previous
//
#include <hip/hip_runtime.h>
#include <hip/hip_bf16.h>

#define NROW 8192
#define DDIM 1024
#define TINV 2.0f   // 1 / TEMPERATURE

typedef __attribute__((ext_vector_type(4))) float f32x4;
typedef __attribute__((ext_vector_type(8))) short short8;

__device__ __forceinline__ ushort f2bf(float f) {
  union { float f; unsigned u; } x; x.f = f;
  unsigned r = x.u + 0x7fffu + ((x.u >> 16) & 1u);  // RNE
  return (ushort)(r >> 16);
}

__device__ __forceinline__ void gload_lds16(const void* g, void* l) {
  __builtin_amdgcn_global_load_lds(
      (const __attribute__((address_space(1))) void*)g,
      (__attribute__((address_space(3))) void*)l, 16, 0, 0);
}

#define SBAR()  __builtin_amdgcn_s_barrier()
#define SCHED() __builtin_amdgcn_sched_barrier(0)
#define PRIO(x) __builtin_amdgcn_s_setprio(x)
#define VMCNT0() asm volatile("s_waitcnt vmcnt(0)" ::: "memory")

// ---------------------------------------------------------------------------
// Kernel 1: per-row L2 norms, diag, bf16 normalized copies (z1 pre-scaled 1/T)
// ---------------------------------------------------------------------------
__global__ __launch_bounds__(256) void normalize_diag(
    const float* __restrict__ v1, const float* __restrict__ v2,
    ushort* __restrict__ z1, ushort* __restrict__ z2,
    float* __restrict__ diag)
{
  const int row = blockIdx.x;
  const int t = threadIdx.x;
  const float4 a = ((const float4*)(v1 + (size_t)row * DDIM))[t];
  const float4 b = ((const float4*)(v2 + (size_t)row * DDIM))[t];
  float s1 = a.x*a.x + a.y*a.y + a.z*a.z + a.w*a.w;
  float s2 = b.x*b.x + b.y*b.y + b.z*b.z + b.w*b.w;
  float sd = a.x*b.x + a.y*b.y + a.z*b.z + a.w*b.w;
  #pragma unroll
  for (int m = 1; m < 64; m <<= 1) {
    s1 += __shfl_xor(s1, m);
    s2 += __shfl_xor(s2, m);
    sd += __shfl_xor(sd, m);
  }
  __shared__ float red[3][4];
  const int w = t >> 6;
  if ((t & 63) == 0) { red[0][w] = s1; red[1][w] = s2; red[2][w] = sd; }
  __syncthreads();
  s1 = red[0][0] + red[0][1] + red[0][2] + red[0][3];
  s2 = red[1][0] + red[1][1] + red[1][2] + red[1][3];
  sd = red[2][0] + red[2][1] + red[2][2] + red[2][3];
  const float i1 = 1.0f / fmaxf(sqrtf(s1), 1e-12f);
  const float i2 = 1.0f / fmaxf(sqrtf(s2), 1e-12f);
  if (t == 0) diag[row] = sd * i1 * i2 * TINV;
  const float sc1 = i1 * TINV;
  ushort4 o1, o2;
  o1.x = f2bf(a.x * sc1); o1.y = f2bf(a.y * sc1);
  o1.z = f2bf(a.z * sc1); o1.w = f2bf(a.w * sc1);
  o2.x = f2bf(b.x * i2);  o2.y = f2bf(b.y * i2);
  o2.z = f2bf(b.z * i2);  o2.w = f2bf(b.w * i2);
  ((ushort4*)(z1 + (size_t)row * DDIM))[t] = o1;
  ((ushort4*)(z2 + (size_t)row * DDIM))[t] = o2;
}

// ---------------------------------------------------------------------------
// Kernel 2: 256x256-tile 8-phase GEMM (sim = z1*z2^T) + fused exp-rowsum.
// 8 waves (2M x 4N), BK=64, double-buffered 128KiB LDS, T2 XOR-swizzle,
// counted vmcnt (one vmcnt(0) per K-tile after last quadrant), T5 setprio.
// Swizzle: LDS elem (row, 8m) holds global k-chunk 8*(m ^ (row&7)); achieved
// by pre-swizzling the *global source* column in the linear global_load_lds.
// ---------------------------------------------------------------------------
#define BM 256
#define BN 256
#define BK 64
#define KTILES (DDIM / BK)

__global__ __launch_bounds__(512, 2) void gemm_rowsum(
    const ushort* __restrict__ z1, const ushort* __restrict__ z2,
    float* __restrict__ partial)
{
  __shared__ __align__(16) ushort As[2][BM * BK];   // 2 x 32 KiB
  __shared__ __align__(16) ushort Bs[2][BN * BK];   // 2 x 32 KiB

  const int bid = blockIdx.x;
  const int bi = bid >> 5;          // 32 row-blocks
  const int bj = bid & 31;          // 32 col-blocks
  const int brow = bi * BM;
  const int bcol = bj * BN;
  const int t = threadIdx.x;
  const int w = t >> 6;             // wave 0..7
  const int lane = t & 63;
  const int wr = w >> 2;            // 0..1: A rows wr*128
  const int wc = w & 3;             // 0..3: B cols wc*64
  const int lcol = lane & 15;
  const int lgrp = lane >> 4;
  const int sr = lane >> 3;         // stage: row within 8-row slab
  const int sc = lane & 7;          // stage: 16B chunk
  const int ssw = ((sc ^ sr) << 3); // pre-swizzled global elem offset

  f32x4 acc[8][4];
  #pragma unroll
  for (int i = 0; i < 8; ++i)
    #pragma unroll
    for (int j = 0; j < 4; ++j)
      acc[i][j] = (f32x4){0.f, 0.f, 0.f, 0.f};

  // ---- staging (linear LDS dest, swizzled global src) ----
#define STAGE_A(S, BUF, K0)                                                   \
  gload_lds16(z1 + (size_t)(brow + (S)*64 + w*8 + sr) * DDIM + (K0) + ssw,    \
              &As[BUF][((S)*64 + w*8) * BK])
#define STAGE_B(S, BUF, K0)                                                   \
  gload_lds16(z2 + (size_t)(bcol + (S)*64 + w*8 + sr) * DDIM + (K0) + ssw,    \
              &Bs[BUF][((S)*64 + w*8) * BK])

  // ---- swizzled ds_read of one MFMA frag ----
#define SWZ(K) ((((K)*4 + lgrp) ^ (lcol & 7)) << 3)
#define READ_A(DST, HALF, BUF)                                                \
  _Pragma("unroll")                                                           \
  for (int m = 0; m < 4; ++m) {                                               \
    const int row_ = wr*128 + ((HALF)*4 + m)*16 + lcol;                       \
    DST[m*2+0] = *(const short8*)&As[BUF][row_*BK + SWZ(0)];                  \
    DST[m*2+1] = *(const short8*)&As[BUF][row_*BK + SWZ(1)];                  \
  }
#define READ_B(DST, HALF, BUF)                                                \
  _Pragma("unroll")                                                           \
  for (int n = 0; n < 2; ++n) {                                               \
    const int row_ = wc*64 + ((HALF)*2 + n)*16 + lcol;                        \
    DST[n*2+0] = *(const short8*)&Bs[BUF][row_*BK + SWZ(0)];                  \
    DST[n*2+1] = *(const short8*)&Bs[BUF][row_*BK + SWZ(1)];                  \
  }

#define QUAD(MB, NB, AA, BB)                                                  \
  _Pragma("unroll")                                                           \
  for (int m = 0; m < 4; ++m)                                                 \
    _Pragma("unroll")                                                         \
    for (int n = 0; n < 2; ++n) {                                             \
      acc[(MB)+m][(NB)+n] = __builtin_amdgcn_mfma_f32_16x16x32_bf16(          \
          AA[m*2+0], BB[n*2+0], acc[(MB)+m][(NB)+n], 0, 0, 0);                \
      acc[(MB)+m][(NB)+n] = __builtin_amdgcn_mfma_f32_16x16x32_bf16(          \
          AA[m*2+1], BB[n*2+1], acc[(MB)+m][(NB)+n], 0, 0, 0);                \
    }

  // prologue: stage K-tile 0 into buf 0
  #pragma unroll
  for (int s = 0; s < 4; ++s) { STAGE_A(s, 0, 0); STAGE_B(s, 0, 0); }
  VMCNT0();
  SBAR();

  short8 a[8], b0[4], b1[4];

  for (int kt = 0; kt < KTILES; ++kt) {
    const int cur = kt & 1, nxt = cur ^ 1;
    const int k1 = (kt + 1) * BK;
    const bool pf = (kt + 1 < KTILES);

    // ---- P1: read A-half0 + B-half0; stage next A rows 0..127 ----
    READ_A(a, 0, cur);
    READ_B(b0, 0, cur);
    if (pf) { STAGE_A(0, nxt, k1); STAGE_A(1, nxt, k1); }
    SCHED(); SBAR(); SCHED();
    PRIO(1); QUAD(0, 0, a, b0); PRIO(0);
    SCHED(); SBAR(); SCHED();

    // ---- P2: read B-half1; stage next A rows 128..255 ----
    READ_B(b1, 1, cur);
    if (pf) { STAGE_A(2, nxt, k1); STAGE_A(3, nxt, k1); }
    SCHED(); SBAR(); SCHED();
    PRIO(1); QUAD(0, 2, a, b1); PRIO(0);
    SCHED(); SBAR(); SCHED();

    // ---- P3: read A-half1 (reuse regs); stage next B (all 4 slabs) ----
    READ_A(a, 1, cur);
    if (pf) { STAGE_B(0, nxt, k1); STAGE_B(1, nxt, k1);
              STAGE_B(2, nxt, k1); STAGE_B(3, nxt, k1); }
    SCHED(); SBAR(); SCHED();
    PRIO(1); QUAD(4, 2, a, b1); PRIO(0);
    SCHED(); SBAR(); SCHED();

    // ---- P4: no reads/stages; MFMA then counted drain for next tile ----
    PRIO(1); QUAD(4, 0, a, b0); PRIO(0);
    SCHED();
    VMCNT0();          // next tile's 8 stage-loads (issued P1-P3) must land
    SBAR();
    SCHED();
  }

  // ---- epilogue: exp + per-row sum over this block's 256 cols ----
  // C/D layout: col = lane&15, row = (lane>>4)*4 + reg.
  float* rs = (float*)&As[0][0];   // [4][256] f32, aliased (safe post-barrier)
  #pragma unroll
  for (int m = 0; m < 8; ++m) {
    #pragma unroll
    for (int r = 0; r < 4; ++r) {
      float s = __expf(acc[m][0][r]) + __expf(acc[m][1][r])
              + __expf(acc[m][2][r]) + __expf(acc[m][3][r]);
      s += __shfl_xor(s, 1);
      s += __shfl_xor(s, 2);
      s += __shfl_xor(s, 4);
      s += __shfl_xor(s, 8);
      if (lcol == 0) rs[wc * 256 + wr * 128 + m * 16 + lgrp * 4 + r] = s;
    }
  }
  __syncthreads();
  if (t < 256)
    partial[(size_t)bj * NROW + brow + t] =
        rs[t] + rs[256 + t] + rs[512 + t] + rs[768 + t];
}

// ---------------------------------------------------------------------------
// Kernel 3: per-row loss = log(sum of 32 partials) - diag; block partial sums.
// ---------------------------------------------------------------------------
__global__ __launch_bounds__(256) void rowloss(
    const float* __restrict__ partial, const float* __restrict__ diag,
    float* __restrict__ blocksum)
{
  const int i = blockIdx.x * 256 + threadIdx.x;
  float s = 0.f;
  #pragma unroll 8
  for (int b = 0; b < 32; ++b) s += partial[(size_t)b * NROW + i];
  float loss = logf(s) - diag[i];
  #pragma unroll
  for (int m = 1; m < 64; m <<= 1) loss += __shfl_xor(loss, m);
  __shared__ float red[4];
  if ((threadIdx.x & 63) == 0) red[threadIdx.x >> 6] = loss;
  __syncthreads();
  if (threadIdx.x == 0)
    blocksum[blockIdx.x] = red[0] + red[1] + red[2] + red[3];
}

__global__ void finalize(const float* __restrict__ blocksum,
                         float* __restrict__ out)
{
  float s = (threadIdx.x < 32) ? blocksum[threadIdx.x] : 0.f;
  #pragma unroll
  for (int m = 1; m < 64; m <<= 1) s += __shfl_xor(s, m);
  if (threadIdx.x == 0) out[0] = s * (1.0f / NROW);
}

// ---------------------------------------------------------------------------
extern "C" void kernel_launch(void* const* d_in, const int* in_sizes, int n_in,
                              void* d_out, int out_size, void* d_ws, size_t ws_size,
                              hipStream_t stream) {
  const float* v1 = (const float*)d_in[0];
  const float* v2 = (const float*)d_in[1];
  float* out = (float*)d_out;

  char* ws = (char*)d_ws;
  // layout: z1 (16MB) | z2 (16MB) | diag (32KB) | partial (1MB) | blocksum
  ushort* z1 = (ushort*)ws;
  ushort* z2 = (ushort*)(ws + (size_t)NROW * DDIM * 2);
  float* diag = (float*)(ws + (size_t)NROW * DDIM * 4);
  float* partial = (float*)(ws + (size_t)NROW * DDIM * 4 + (size_t)NROW * 4);
  float* blocksum = (float*)(ws + (size_t)NROW * DDIM * 4 + (size_t)NROW * 4
                             + (size_t)32 * NROW * 4);

  normalize_diag<<<NROW, 256, 0, stream>>>(v1, v2, z1, z2, diag);
  gemm_rowsum<<<(NROW / BM) * (NROW / BN), 512, 0, stream>>>(z1, z2, partial);
  rowloss<<<NROW / 256, 256, 0, stream>>>(partial, diag, blocksum);
  finalize<<<1, 64, 0, stream>>>(blocksum, out);
}

// Round 3
// 161.756 us; speedup vs baseline: 1.1745x; 1.0520x over previous
//
#include <hip/hip_runtime.h>
#include <hip/hip_bf16.h>

#define NROW 8192
#define DDIM 1024
#define TINV 2.0f   // 1 / TEMPERATURE

typedef __attribute__((ext_vector_type(4))) float f32x4;
typedef __attribute__((ext_vector_type(8))) short short8;

__device__ __forceinline__ ushort f2bf(float f) {
  union { float f; unsigned u; } x; x.f = f;
  unsigned r = x.u + 0x7fffu + ((x.u >> 16) & 1u);  // RNE
  return (ushort)(r >> 16);
}

__device__ __forceinline__ void gload_lds16(const void* g, void* l) {
  __builtin_amdgcn_global_load_lds(
      (const __attribute__((address_space(1))) void*)g,
      (__attribute__((address_space(3))) void*)l, 16, 0, 0);
}

#define SBAR()  __builtin_amdgcn_s_barrier()
#define SCHED() __builtin_amdgcn_sched_barrier(0)
#define PRIO(x) __builtin_amdgcn_s_setprio(x)
#define VMCNT(N) asm volatile("s_waitcnt vmcnt(" #N ")" ::: "memory")

// ---------------------------------------------------------------------------
// Kernel 1: per-row L2 norms, diag, bf16 normalized copies (z1 pre-scaled 1/T)
// ---------------------------------------------------------------------------
__global__ __launch_bounds__(256) void normalize_diag(
    const float* __restrict__ v1, const float* __restrict__ v2,
    ushort* __restrict__ z1, ushort* __restrict__ z2,
    float* __restrict__ diag)
{
  const int row = blockIdx.x;
  const int t = threadIdx.x;
  const float4 a = ((const float4*)(v1 + (size_t)row * DDIM))[t];
  const float4 b = ((const float4*)(v2 + (size_t)row * DDIM))[t];
  float s1 = a.x*a.x + a.y*a.y + a.z*a.z + a.w*a.w;
  float s2 = b.x*b.x + b.y*b.y + b.z*b.z + b.w*b.w;
  float sd = a.x*b.x + a.y*b.y + a.z*b.z + a.w*b.w;
  #pragma unroll
  for (int m = 1; m < 64; m <<= 1) {
    s1 += __shfl_xor(s1, m);
    s2 += __shfl_xor(s2, m);
    sd += __shfl_xor(sd, m);
  }
  __shared__ float red[3][4];
  const int w = t >> 6;
  if ((t & 63) == 0) { red[0][w] = s1; red[1][w] = s2; red[2][w] = sd; }
  __syncthreads();
  s1 = red[0][0] + red[0][1] + red[0][2] + red[0][3];
  s2 = red[1][0] + red[1][1] + red[1][2] + red[1][3];
  sd = red[2][0] + red[2][1] + red[2][2] + red[2][3];
  const float i1 = 1.0f / fmaxf(sqrtf(s1), 1e-12f);
  const float i2 = 1.0f / fmaxf(sqrtf(s2), 1e-12f);
  if (t == 0) diag[row] = sd * i1 * i2 * TINV;
  const float sc1 = i1 * TINV;
  ushort4 o1, o2;
  o1.x = f2bf(a.x * sc1); o1.y = f2bf(a.y * sc1);
  o1.z = f2bf(a.z * sc1); o1.w = f2bf(a.w * sc1);
  o2.x = f2bf(b.x * i2);  o2.y = f2bf(b.y * i2);
  o2.z = f2bf(b.z * i2);  o2.w = f2bf(b.w * i2);
  ((ushort4*)(z1 + (size_t)row * DDIM))[t] = o1;
  ((ushort4*)(z2 + (size_t)row * DDIM))[t] = o2;
}

// ---------------------------------------------------------------------------
// Kernel 2: 256x256-tile GEMM (sim = z1*z2^T) + fused exp-rowsum.
// 8 waves (2M x 4N), BK=64, 2-buffer LDS, T2 XOR-swizzle (0 conflicts),
// COUNTED vmcnt pipeline: tile kt+2 staged entirely in P4 of tile kt;
// end-of-tile wait = vmcnt(8) (tile kt+1 landed, kt+2's 8 loads stay in
// flight across the barrier -> no drain in main loop). T5 setprio.
// ---------------------------------------------------------------------------
#define BM 256
#define BN 256
#define BK 64
#define KTILES (DDIM / BK)

__global__ __launch_bounds__(512, 2) void gemm_rowsum(
    const ushort* __restrict__ z1, const ushort* __restrict__ z2,
    float* __restrict__ partial)
{
  __shared__ __align__(16) ushort As[2][BM * BK];   // 2 x 32 KiB
  __shared__ __align__(16) ushort Bs[2][BN * BK];   // 2 x 32 KiB

  const int bid = blockIdx.x;
  const int bi = bid >> 5;          // 32 row-blocks
  const int bj = bid & 31;          // 32 col-blocks
  const int brow = bi * BM;
  const int bcol = bj * BN;
  const int t = threadIdx.x;
  const int w = t >> 6;             // wave 0..7
  const int lane = t & 63;
  const int wr = w >> 2;            // 0..1: A rows wr*128
  const int wc = w & 3;             // 0..3: B cols wc*64
  const int lcol = lane & 15;
  const int lgrp = lane >> 4;
  const int sr = lane >> 3;         // stage: row within 8-row slab
  const int sc = lane & 7;          // stage: 16B chunk
  const int ssw = ((sc ^ sr) << 3); // pre-swizzled global elem offset

  f32x4 acc[8][4];
  #pragma unroll
  for (int i = 0; i < 8; ++i)
    #pragma unroll
    for (int j = 0; j < 4; ++j)
      acc[i][j] = (f32x4){0.f, 0.f, 0.f, 0.f};

  // ---- staging (linear LDS dest, swizzled global src) ----
#define STAGE_A(S, BUF, K0)                                                   \
  gload_lds16(z1 + (size_t)(brow + (S)*64 + w*8 + sr) * DDIM + (K0) + ssw,    \
              &As[BUF][((S)*64 + w*8) * BK])
#define STAGE_B(S, BUF, K0)                                                   \
  gload_lds16(z2 + (size_t)(bcol + (S)*64 + w*8 + sr) * DDIM + (K0) + ssw,    \
              &Bs[BUF][((S)*64 + w*8) * BK])
#define STAGE_TILE(BUF, K0)                                                   \
  do { STAGE_A(0, BUF, K0); STAGE_A(1, BUF, K0);                              \
       STAGE_A(2, BUF, K0); STAGE_A(3, BUF, K0);                              \
       STAGE_B(0, BUF, K0); STAGE_B(1, BUF, K0);                              \
       STAGE_B(2, BUF, K0); STAGE_B(3, BUF, K0); } while (0)

  // ---- swizzled ds_read of one MFMA frag ----
#define SWZ(K) ((((K)*4 + lgrp) ^ (lcol & 7)) << 3)
#define READ_A(DST, HALF, BUF)                                                \
  _Pragma("unroll")                                                           \
  for (int m = 0; m < 4; ++m) {                                               \
    const int row_ = wr*128 + ((HALF)*4 + m)*16 + lcol;                       \
    DST[m*2+0] = *(const short8*)&As[BUF][row_*BK + SWZ(0)];                  \
    DST[m*2+1] = *(const short8*)&As[BUF][row_*BK + SWZ(1)];                  \
  }
#define READ_B(DST, HALF, BUF)                                                \
  _Pragma("unroll")                                                           \
  for (int n = 0; n < 2; ++n) {                                               \
    const int row_ = wc*64 + ((HALF)*2 + n)*16 + lcol;                        \
    DST[n*2+0] = *(const short8*)&Bs[BUF][row_*BK + SWZ(0)];                  \
    DST[n*2+1] = *(const short8*)&Bs[BUF][row_*BK + SWZ(1)];                  \
  }

#define QUAD(MB, NB, AA, BB)                                                  \
  _Pragma("unroll")                                                           \
  for (int m = 0; m < 4; ++m)                                                 \
    _Pragma("unroll")                                                         \
    for (int n = 0; n < 2; ++n) {                                             \
      acc[(MB)+m][(NB)+n] = __builtin_amdgcn_mfma_f32_16x16x32_bf16(          \
          AA[m*2+0], BB[n*2+0], acc[(MB)+m][(NB)+n], 0, 0, 0);                \
      acc[(MB)+m][(NB)+n] = __builtin_amdgcn_mfma_f32_16x16x32_bf16(          \
          AA[m*2+1], BB[n*2+1], acc[(MB)+m][(NB)+n], 0, 0, 0);                \
    }

  // prologue: stage tile 0 -> buf0, tile 1 -> buf1; counted wait for tile 0
  STAGE_TILE(0, 0);
  STAGE_TILE(1, BK);
  VMCNT(8);          // tile 0's 8 loads landed; tile 1's stay in flight
  SBAR();

  short8 a[8], b0[4], b1[4];

  #pragma unroll 2
  for (int kt = 0; kt < KTILES; ++kt) {
    const int cur = kt & 1;
    const int k2 = (kt + 2) * BK;

    // ---- P1 ----
    READ_A(a, 0, cur);
    READ_B(b0, 0, cur);
    SCHED(); SBAR(); SCHED();
    PRIO(1); QUAD(0, 0, a, b0); PRIO(0);
    SCHED(); SBAR(); SCHED();

    // ---- P2 ----
    READ_B(b1, 1, cur);
    SCHED(); SBAR(); SCHED();
    PRIO(1); QUAD(0, 2, a, b1); PRIO(0);
    SCHED(); SBAR(); SCHED();

    // ---- P3 (last reads of buf[cur]) ----
    READ_A(a, 1, cur);
    SCHED(); SBAR(); SCHED();
    PRIO(1); QUAD(4, 2, a, b1); PRIO(0);
    SCHED(); SBAR(); SCHED();

    // ---- P4: stage tile kt+2 into buf[cur] (reads done), MFMA, counted wait
    if (kt + 2 < KTILES) STAGE_TILE(cur, k2);
    PRIO(1); QUAD(4, 0, a, b0); PRIO(0);
    SCHED();
    if (kt + 2 < KTILES)       VMCNT(8);   // tile kt+1 ready; kt+2 in flight
    else if (kt + 1 < KTILES)  VMCNT(0);   // kt==14: drain last tile
    SBAR(); SCHED();
  }

  // ---- epilogue: exp + per-row sum over this block's 256 cols ----
  // C/D layout: col = lane&15, row = (lane>>4)*4 + reg.
  float* rs = (float*)&As[0][0];   // [4][256] f32, aliased (all loads drained)
  #pragma unroll
  for (int m = 0; m < 8; ++m) {
    #pragma unroll
    for (int r = 0; r < 4; ++r) {
      float s = __expf(acc[m][0][r]) + __expf(acc[m][1][r])
              + __expf(acc[m][2][r]) + __expf(acc[m][3][r]);
      s += __shfl_xor(s, 1);
      s += __shfl_xor(s, 2);
      s += __shfl_xor(s, 4);
      s += __shfl_xor(s, 8);
      if (lcol == 0) rs[wc * 256 + wr * 128 + m * 16 + lgrp * 4 + r] = s;
    }
  }
  __syncthreads();
  if (t < 256)
    partial[(size_t)bj * NROW + brow + t] =
        rs[t] + rs[256 + t] + rs[512 + t] + rs[768 + t];
}

// ---------------------------------------------------------------------------
// Kernel 3: per-row loss = log(sum of 32 partials) - diag; block partial sums.
// ---------------------------------------------------------------------------
__global__ __launch_bounds__(256) void rowloss(
    const float* __restrict__ partial, const float* __restrict__ diag,
    float* __restrict__ blocksum)
{
  const int i = blockIdx.x * 256 + threadIdx.x;
  float s = 0.f;
  #pragma unroll 8
  for (int b = 0; b < 32; ++b) s += partial[(size_t)b * NROW + i];
  float loss = logf(s) - diag[i];
  #pragma unroll
  for (int m = 1; m < 64; m <<= 1) loss += __shfl_xor(loss, m);
  __shared__ float red[4];
  if ((threadIdx.x & 63) == 0) red[threadIdx.x >> 6] = loss;
  __syncthreads();
  if (threadIdx.x == 0)
    blocksum[blockIdx.x] = red[0] + red[1] + red[2] + red[3];
}

__global__ void finalize(const float* __restrict__ blocksum,
                         float* __restrict__ out)
{
  float s = (threadIdx.x < 32) ? blocksum[threadIdx.x] : 0.f;
  #pragma unroll
  for (int m = 1; m < 64; m <<= 1) s += __shfl_xor(s, m);
  if (threadIdx.x == 0) out[0] = s * (1.0f / NROW);
}

// ---------------------------------------------------------------------------
extern "C" void kernel_launch(void* const* d_in, const int* in_sizes, int n_in,
                              void* d_out, int out_size, void* d_ws, size_t ws_size,
                              hipStream_t stream) {
  const float* v1 = (const float*)d_in[0];
  const float* v2 = (const float*)d_in[1];
  float* out = (float*)d_out;

  char* ws = (char*)d_ws;
  // layout: z1 (16MB) | z2 (16MB) | diag (32KB) | partial (1MB) | blocksum
  ushort* z1 = (ushort*)ws;
  ushort* z2 = (ushort*)(ws + (size_t)NROW * DDIM * 2);
  float* diag = (float*)(ws + (size_t)NROW * DDIM * 4);
  float* partial = (float*)(ws + (size_t)NROW * DDIM * 4 + (size_t)NROW * 4);
  float* blocksum = (float*)(ws + (size_t)NROW * DDIM * 4 + (size_t)NROW * 4
                             + (size_t)32 * NROW * 4);

  normalize_diag<<<NROW, 256, 0, stream>>>(v1, v2, z1, z2, diag);
  gemm_rowsum<<<(NROW / BM) * (NROW / BN), 512, 0, stream>>>(z1, z2, partial);
  rowloss<<<NROW / 256, 256, 0, stream>>>(partial, diag, blocksum);
  finalize<<<1, 64, 0, stream>>>(blocksum, out);
}

// Round 4
// 154.580 us; speedup vs baseline: 1.2290x; 1.0464x over previous
//
#include <hip/hip_runtime.h>
#include <hip/hip_bf16.h>

#define NROW 8192
#define DDIM 1024
#define TINV 2.0f   // 1 / TEMPERATURE

typedef __attribute__((ext_vector_type(4))) float f32x4;
typedef __attribute__((ext_vector_type(8))) short short8;

__device__ __forceinline__ ushort f2bf(float f) {
  union { float f; unsigned u; } x; x.f = f;
  unsigned r = x.u + 0x7fffu + ((x.u >> 16) & 1u);  // RNE
  return (ushort)(r >> 16);
}

__device__ __forceinline__ void gload_lds16(const void* g, void* l) {
  __builtin_amdgcn_global_load_lds(
      (const __attribute__((address_space(1))) void*)g,
      (__attribute__((address_space(3))) void*)l, 16, 0, 0);
}

#define SBAR()  __builtin_amdgcn_s_barrier()
#define PRIO(x) __builtin_amdgcn_s_setprio(x)
#define VMCNT(N) asm volatile("s_waitcnt vmcnt(" #N ")" ::: "memory")

// ---------------------------------------------------------------------------
// Kernel 1: per-row L2 norms, diag, bf16 normalized copies (z1 pre-scaled 1/T)
// ---------------------------------------------------------------------------
__global__ __launch_bounds__(256) void normalize_diag(
    const float* __restrict__ v1, const float* __restrict__ v2,
    ushort* __restrict__ z1, ushort* __restrict__ z2,
    float* __restrict__ diag)
{
  const int row = blockIdx.x;
  const int t = threadIdx.x;
  const float4 a = ((const float4*)(v1 + (size_t)row * DDIM))[t];
  const float4 b = ((const float4*)(v2 + (size_t)row * DDIM))[t];
  float s1 = a.x*a.x + a.y*a.y + a.z*a.z + a.w*a.w;
  float s2 = b.x*b.x + b.y*b.y + b.z*b.z + b.w*b.w;
  float sd = a.x*b.x + a.y*b.y + a.z*b.z + a.w*b.w;
  #pragma unroll
  for (int m = 1; m < 64; m <<= 1) {
    s1 += __shfl_xor(s1, m);
    s2 += __shfl_xor(s2, m);
    sd += __shfl_xor(sd, m);
  }
  __shared__ float red[3][4];
  const int w = t >> 6;
  if ((t & 63) == 0) { red[0][w] = s1; red[1][w] = s2; red[2][w] = sd; }
  __syncthreads();
  s1 = red[0][0] + red[0][1] + red[0][2] + red[0][3];
  s2 = red[1][0] + red[1][1] + red[1][2] + red[1][3];
  sd = red[2][0] + red[2][1] + red[2][2] + red[2][3];
  const float i1 = 1.0f / fmaxf(sqrtf(s1), 1e-12f);
  const float i2 = 1.0f / fmaxf(sqrtf(s2), 1e-12f);
  if (t == 0) diag[row] = sd * i1 * i2 * TINV;
  const float sc1 = i1 * TINV;
  ushort4 o1, o2;
  o1.x = f2bf(a.x * sc1); o1.y = f2bf(a.y * sc1);
  o1.z = f2bf(a.z * sc1); o1.w = f2bf(a.w * sc1);
  o2.x = f2bf(b.x * i2);  o2.y = f2bf(b.y * i2);
  o2.z = f2bf(b.z * i2);  o2.w = f2bf(b.w * i2);
  ((ushort4*)(z1 + (size_t)row * DDIM))[t] = o1;
  ((ushort4*)(z2 + (size_t)row * DDIM))[t] = o2;
}

// ---------------------------------------------------------------------------
// Kernel 2: 256x256-tile GEMM (sim = z1*z2^T) + fused exp-rowsum.
// 8 waves (2M x 4N), BK=64, 2-buffer LDS, T2 XOR-swizzle (0 conflicts),
// counted-vmcnt pipeline, stages spread P3(B)/P4(A), NO sched pinning
// (compiler emits fine-grained lgkmcnt; m141 lesson), T5 setprio.
// Buffer lifetime: B[cur] reads done by post-P2 barrier -> stage B at P3;
// A[cur] reads done by post-P3 barrier -> stage A at P4. Tile kt stages
// tile kt+2 into buf[cur]; tile-end VMCNT(8) = kt+1 landed, kt+2 in flight.
// ---------------------------------------------------------------------------
#define BM 256
#define BN 256
#define BK 64
#define KTILES (DDIM / BK)

__global__ __launch_bounds__(512, 2) void gemm_rowsum(
    const ushort* __restrict__ z1, const ushort* __restrict__ z2,
    float* __restrict__ partial)
{
  __shared__ __align__(16) ushort As[2][BM * BK];   // 2 x 32 KiB
  __shared__ __align__(16) ushort Bs[2][BN * BK];   // 2 x 32 KiB

  const int bid = blockIdx.x;
  const int bi = bid >> 5;          // 32 row-blocks
  const int bj = bid & 31;          // 32 col-blocks
  const int brow = bi * BM;
  const int bcol = bj * BN;
  const int t = threadIdx.x;
  const int w = t >> 6;             // wave 0..7
  const int lane = t & 63;
  const int wr = w >> 2;            // 0..1: A rows wr*128
  const int wc = w & 3;             // 0..3: B cols wc*64
  const int lcol = lane & 15;
  const int lgrp = lane >> 4;
  const int sr = lane >> 3;         // stage: row within 8-row slab
  const int sc = lane & 7;          // stage: 16B chunk
  const int ssw = ((sc ^ sr) << 3); // pre-swizzled global elem offset

  f32x4 acc[8][4];
  #pragma unroll
  for (int i = 0; i < 8; ++i)
    #pragma unroll
    for (int j = 0; j < 4; ++j)
      acc[i][j] = (f32x4){0.f, 0.f, 0.f, 0.f};

  // ---- staging (linear LDS dest, swizzled global src) ----
#define STAGE_A(S, BUF, K0)                                                   \
  gload_lds16(z1 + (size_t)(brow + (S)*64 + w*8 + sr) * DDIM + (K0) + ssw,    \
              &As[BUF][((S)*64 + w*8) * BK])
#define STAGE_B(S, BUF, K0)                                                   \
  gload_lds16(z2 + (size_t)(bcol + (S)*64 + w*8 + sr) * DDIM + (K0) + ssw,    \
              &Bs[BUF][((S)*64 + w*8) * BK])

  // ---- swizzled ds_read of one MFMA frag ----
#define SWZ(K) ((((K)*4 + lgrp) ^ (lcol & 7)) << 3)
#define READ_A(DST, HALF, BUF)                                                \
  _Pragma("unroll")                                                           \
  for (int m = 0; m < 4; ++m) {                                               \
    const int row_ = wr*128 + ((HALF)*4 + m)*16 + lcol;                       \
    DST[m*2+0] = *(const short8*)&As[BUF][row_*BK + SWZ(0)];                  \
    DST[m*2+1] = *(const short8*)&As[BUF][row_*BK + SWZ(1)];                  \
  }
#define READ_B(DST, HALF, BUF)                                                \
  _Pragma("unroll")                                                           \
  for (int n = 0; n < 2; ++n) {                                               \
    const int row_ = wc*64 + ((HALF)*2 + n)*16 + lcol;                        \
    DST[n*2+0] = *(const short8*)&Bs[BUF][row_*BK + SWZ(0)];                  \
    DST[n*2+1] = *(const short8*)&Bs[BUF][row_*BK + SWZ(1)];                  \
  }

#define QUAD(MB, NB, AA, BB)                                                  \
  _Pragma("unroll")                                                           \
  for (int m = 0; m < 4; ++m)                                                 \
    _Pragma("unroll")                                                         \
    for (int n = 0; n < 2; ++n) {                                             \
      acc[(MB)+m][(NB)+n] = __builtin_amdgcn_mfma_f32_16x16x32_bf16(          \
          AA[m*2+0], BB[n*2+0], acc[(MB)+m][(NB)+n], 0, 0, 0);                \
      acc[(MB)+m][(NB)+n] = __builtin_amdgcn_mfma_f32_16x16x32_bf16(          \
          AA[m*2+1], BB[n*2+1], acc[(MB)+m][(NB)+n], 0, 0, 0);                \
    }

  // prologue: stage tile 0 -> buf0, tile 1 -> buf1; counted wait for tile 0
  #pragma unroll
  for (int s = 0; s < 4; ++s) { STAGE_A(s, 0, 0); STAGE_B(s, 0, 0); }
  #pragma unroll
  for (int s = 0; s < 4; ++s) { STAGE_A(s, 1, BK); STAGE_B(s, 1, BK); }
  VMCNT(8);          // tile 0's 8 loads landed; tile 1's stay in flight
  SBAR();

  short8 a[8], b0[4], b1[4];

  #pragma unroll 2
  for (int kt = 0; kt < KTILES; ++kt) {
    const int cur = kt & 1;
    const int k2 = (kt + 2) * BK;
    const bool pf2 = (kt + 2 < KTILES);

    // ---- P1: read A-half0 (8) + B-half0 (4) ----
    READ_A(a, 0, cur);
    READ_B(b0, 0, cur);
    SBAR();
    PRIO(1); QUAD(0, 0, a, b0); PRIO(0);
    SBAR();

    // ---- P2: read B-half1 (4); last reads of Bs[cur] ----
    READ_B(b1, 1, cur);
    SBAR();
    PRIO(1); QUAD(0, 2, a, b1); PRIO(0);
    SBAR();

    // ---- P3: read A-half1 (8, last reads of As[cur]); stage next-next B ----
    READ_A(a, 1, cur);
    if (pf2) { STAGE_B(0, cur, k2); STAGE_B(1, cur, k2);
               STAGE_B(2, cur, k2); STAGE_B(3, cur, k2); }
    SBAR();
    PRIO(1); QUAD(4, 2, a, b1); PRIO(0);
    SBAR();

    // ---- P4: stage next-next A; MFMA; counted tile-boundary wait ----
    if (pf2) { STAGE_A(0, cur, k2); STAGE_A(1, cur, k2);
               STAGE_A(2, cur, k2); STAGE_A(3, cur, k2); }
    PRIO(1); QUAD(4, 0, a, b0); PRIO(0);
    if (pf2)                   VMCNT(8);   // kt+1 ready; kt+2 in flight
    else if (kt + 1 < KTILES)  VMCNT(0);   // kt==14: drain last tile
    SBAR();
  }

  // ---- epilogue: exp + per-row sum over this block's 256 cols ----
  // C/D layout: col = lane&15, row = (lane>>4)*4 + reg.
  float* rs = (float*)&As[0][0];   // [4][256] f32, aliased (all loads drained)
  #pragma unroll
  for (int m = 0; m < 8; ++m) {
    #pragma unroll
    for (int r = 0; r < 4; ++r) {
      float s = __expf(acc[m][0][r]) + __expf(acc[m][1][r])
              + __expf(acc[m][2][r]) + __expf(acc[m][3][r]);
      s += __shfl_xor(s, 1);
      s += __shfl_xor(s, 2);
      s += __shfl_xor(s, 4);
      s += __shfl_xor(s, 8);
      if (lcol == 0) rs[wc * 256 + wr * 128 + m * 16 + lgrp * 4 + r] = s;
    }
  }
  __syncthreads();
  if (t < 256)
    partial[(size_t)bj * NROW + brow + t] =
        rs[t] + rs[256 + t] + rs[512 + t] + rs[768 + t];
}

// ---------------------------------------------------------------------------
// Kernel 3: per-row loss = log(sum of 32 partials) - diag; block partial sums.
// ---------------------------------------------------------------------------
__global__ __launch_bounds__(256) void rowloss(
    const float* __restrict__ partial, const float* __restrict__ diag,
    float* __restrict__ blocksum)
{
  const int i = blockIdx.x * 256 + threadIdx.x;
  float s = 0.f;
  #pragma unroll 8
  for (int b = 0; b < 32; ++b) s += partial[(size_t)b * NROW + i];
  float loss = logf(s) - diag[i];
  #pragma unroll
  for (int m = 1; m < 64; m <<= 1) loss += __shfl_xor(loss, m);
  __shared__ float red[4];
  if ((threadIdx.x & 63) == 0) red[threadIdx.x >> 6] = loss;
  __syncthreads();
  if (threadIdx.x == 0)
    blocksum[blockIdx.x] = red[0] + red[1] + red[2] + red[3];
}

__global__ void finalize(const float* __restrict__ blocksum,
                         float* __restrict__ out)
{
  float s = (threadIdx.x < 32) ? blocksum[threadIdx.x] : 0.f;
  #pragma unroll
  for (int m = 1; m < 64; m <<= 1) s += __shfl_xor(s, m);
  if (threadIdx.x == 0) out[0] = s * (1.0f / NROW);
}

// ---------------------------------------------------------------------------
extern "C" void kernel_launch(void* const* d_in, const int* in_sizes, int n_in,
                              void* d_out, int out_size, void* d_ws, size_t ws_size,
                              hipStream_t stream) {
  const float* v1 = (const float*)d_in[0];
  const float* v2 = (const float*)d_in[1];
  float* out = (float*)d_out;

  char* ws = (char*)d_ws;
  // layout: z1 (16MB) | z2 (16MB) | diag (32KB) | partial (1MB) | blocksum
  ushort* z1 = (ushort*)ws;
  ushort* z2 = (ushort*)(ws + (size_t)NROW * DDIM * 2);
  float* diag = (float*)(ws + (size_t)NROW * DDIM * 4);
  float* partial = (float*)(ws + (size_t)NROW * DDIM * 4 + (size_t)NROW * 4);
  float* blocksum = (float*)(ws + (size_t)NROW * DDIM * 4 + (size_t)NROW * 4
                             + (size_t)32 * NROW * 4);

  normalize_diag<<<NROW, 256, 0, stream>>>(v1, v2, z1, z2, diag);
  gemm_rowsum<<<(NROW / BM) * (NROW / BN), 512, 0, stream>>>(z1, z2, partial);
  rowloss<<<NROW / 256, 256, 0, stream>>>(partial, diag, blocksum);
  finalize<<<1, 64, 0, stream>>>(blocksum, out);
}